// Round 10
// baseline (1144.372 us; speedup 1.0000x reference)
//
#include <hip/hip_runtime.h>
#include <hip/hip_bf16.h>

// LIF fused kernel, Round 13: 4-way finisher + 4t/barrier + plane-major xq
//                             + b32 bits loads. Output bit-identical to R12.
//
// R12 post-mortem: 506->425us as predicted. Wall 996 cy/t = VALU ~625 +
// idle ~170 (finisher tail + barrier) with MFMA (205) fully overlapped.
// R13 residual fixes (no arithmetic change -- int sums are order-free):
//  a. finisher split 4-way: wq0..3 own acc row r=wq (1 neuron/lane).
//  b. 4 timesteps per barrier: 8 xq slots (64KB LDS, 2 blocks/CU kept);
//     produce-first then finish so MFMA latency hides under finisher VALU.
//  c. plane-major xq [slot][r][wq*64+lane]: producer 4x ds_write_b32 and
//     finisher reads both at 4B lane stride -> zero bank conflicts
//     (R12's lane*16B read stride was a 4-way conflict).
//  d. bits load b32 (lane uses 16 bits; dword = wq*2 + (lq>>1)) -> halves
//     bits L2 traffic (4->2KB/block/t).
// i8 engine (3-digit W quant, mfma_i32_16x16x64_i8, exact-int combine)
// unchanged from R12.
//
// Packed layout: bits[t*4096 + b*16 + wd], bit j (LSB) = spike[t][b][wd*32+j].

typedef __attribute__((ext_vector_type(8))) short short8;   // 8 x bf16
typedef __attribute__((ext_vector_type(4))) float floatx4;
typedef __attribute__((ext_vector_type(2))) unsigned uintx2;
typedef __attribute__((ext_vector_type(4))) int int4v;

#define T_STEPS 1024
#define B_DIM   256
#define F_DIM   512
#define BF      (B_DIM * F_DIM)
#define ROWP    520   // (fallback kernel only)

static __device__ __forceinline__ unsigned short f2bf_rne(float f) {
    unsigned u = __float_as_uint(f);
    return (unsigned short)((u + 0x7FFFu + ((u >> 16) & 1u)) >> 16);
}
static __device__ __forceinline__ float bf2f(unsigned short h) {
    return __uint_as_float(((unsigned)h) << 16);
}

// ---------------- prepass: fp32 {0,1} -> bitmask ----------------
__global__ __launch_bounds__(256)
void pack_kernel(const float* __restrict__ sp, unsigned* __restrict__ bits)
{
    const int lane = threadIdx.x & 63;
    const int wv   = blockIdx.x * 4 + (threadIdx.x >> 6);
    for (int c = wv; c < 65536; c += 2048 * 4) {
        const float* p = sp + (size_t)c * 2048;
        unsigned val = 0;
        #pragma unroll
        for (int r = 0; r < 32; ++r) {
            float x = p[r * 64 + lane];
            unsigned long long m = __ballot(x != 0.0f);
            unsigned sel = (lane & 1) ? (unsigned)(m >> 32) : (unsigned)m;
            if ((lane >> 1) == r) val = sel;
        }
        bits[(size_t)c * 64 + lane] = val;
    }
}

// -------- main kernel: i8 engine, 4t/barrier, 4-way finisher ------------
__global__ __launch_bounds__(512, 4)
void lif_kernel_bits(const unsigned* __restrict__ bits,
                     const float* __restrict__ W,
                     float* __restrict__ out)
{
    __shared__ int   xq[8][4][512];    // [slot][r][wq*64+lane] int partials
    __shared__ float rowmax[8][16];    // setup-only

    const int tid  = threadIdx.x;
    const int lane = tid & 63;
    const int wq   = tid >> 6;          // 0..7: K-eighth, k in [wq*64, +64)
    const int bt   = blockIdx.x & 15;
    const int gb   = blockIdx.x >> 4;   // 0..31
    const int b0   = bt * 16;
    const int gw   = gb * 16;
    const int mrow = lane & 15;
    const int lq   = lane >> 4;         // 0..3: k-chunk of 16 within the 64

    // ---- W setup (once): rows gw+mrow, k = wq*64 + lq*16 + j  [R12 code]
    int4v wi0, wi1, wi2;
    float invC;
    {
        const float* wp = W + (size_t)(gw + mrow) * F_DIM + wq * 64 + lq * 16;
        float wv[16];
        float lm = 0.0f;
        #pragma unroll
        for (int j = 0; j < 16; ++j) {
            wv[j] = wp[j];
            lm = fmaxf(lm, fabsf(wv[j]));
        }
        lm = fmaxf(lm, __shfl_xor(lm, 16, 64));
        lm = fmaxf(lm, __shfl_xor(lm, 32, 64));
        if (lane < 16) rowmax[wq][lane] = lm;
        __syncthreads();
        float S = 1e-30f;
        #pragma unroll
        for (int w8 = 0; w8 < 8; ++w8) S = fmaxf(S, rowmax[w8][mrow]);
        __syncthreads();   // rowmax consumed before xq activity
        const float C = 8000000.0f / S;
        invC = S / 8000000.0f;
        #pragma unroll
        for (int d = 0; d < 4; ++d) {
            unsigned p0 = 0, p1 = 0, p2 = 0;
            #pragma unroll
            for (int jj = 0; jj < 4; ++jj) {
                int q  = __float2int_rn(wv[d * 4 + jj] * C);
                int d2 = (q << 24) >> 24;          // sext low byte
                int r1 = (q - d2) >> 8;            // exact (divisible)
                int d1 = (r1 << 24) >> 24;
                int d0 = (r1 - d1) >> 8;           // |d0| <= 123
                p0 |= (unsigned)(d0 & 0xFF) << (8 * jj);
                p1 |= (unsigned)(d1 & 0xFF) << (8 * jj);
                p2 |= (unsigned)(d2 & 0xFF) << (8 * jj);
            }
            wi0[d] = (int)p0; wi1[d] = (int)p1; wi2[d] = (int)p2;
        }
    }

    // ---- LIF state: 4-way finisher. wq0..3 own acc row r = wq.
    // neuron (b,g) = (b0 + lq*4 + wq, gw + mrow).
    const bool fin  = (wq < 4);
    const int  rown = wq & 3;
    float v0 = 0.f, c0 = 0.f, z0 = 0.f;

    // bits: one b32/lane/t. dword = row*16 + wq*2 + (lq>>1); half by lq&1.
    const unsigned* bp = bits + (size_t)(b0 + mrow) * 16 + wq * 2 + (lq >> 1);
    const int hsh = (lq & 1) * 16;

    auto ldbits = [&](int t) -> unsigned {
        return bp[(size_t)t * 4096];
    };

    // expand 16 bits -> 16 i8 bytes {0,1}: nibble * 0x204081 spreads bit j
    // to byte j (no carries); mask keeps LSBs.
    auto expand = [&](unsigned dw) -> int4v {
        unsigned h16 = dw >> hsh;
        int4v a;
        #pragma unroll
        for (int d = 0; d < 4; ++d) {
            unsigned b4 = (h16 >> (4 * d)) & 0xFu;
            a[d] = (int)((b4 * 0x00204081u) & 0x01010101u);
        }
        return a;
    };

    const int4v iz = {0, 0, 0, 0};

    // 3 exact-int MFMAs + exact-int combine (|c| <= 5.2e8)
    auto mci = [&](int4v aI) -> int4v {
        int4v a0 = __builtin_amdgcn_mfma_i32_16x16x64_i8(aI, wi0, iz, 0, 0, 0);
        int4v a1 = __builtin_amdgcn_mfma_i32_16x16x64_i8(aI, wi1, iz, 0, 0, 0);
        int4v a2 = __builtin_amdgcn_mfma_i32_16x16x64_i8(aI, wi2, iz, 0, 0, 0);
        int4v c;
        #pragma unroll
        for (int r = 0; r < 4; ++r)
            c[r] = ((a0[r] << 16) + (a1[r] << 8)) + a2[r];
        return c;
    };

    // producer: plane-major scatter, conflict-free b32 writes
    auto wrpart = [&](int slot, int4v c) {
        #pragma unroll
        for (int r = 0; r < 4; ++r)
            xq[slot][r][wq * 64 + lane] = c[r];
    };

    // finisher: exact-int sum of 8 partials of row rown, 1 cvt, LIF
    auto lif1 = [&](int slot) {
        const int* p = &xq[slot][rown][lane];
        int s = 0;
        #pragma unroll
        for (int w8 = 0; w8 < 8; ++w8)
            s += p[w8 * 64];
        float x  = (float)s * invC;
        float vd = v0 + 0.1f * ((0.0f - v0) + c0);   // DT*TAU_MEM_INV
        float id = c0 - 0.2f * c0;                    // DT*TAU_SYN_INV
        bool  sp = (vd - 1.0f) > 0.0f;                // heaviside
        z0 = sp ? 1.0f : 0.0f;
        v0 = sp ? 0.0f : vd;                          // V_RESET = 0
        c0 = id + x;
    };

    unsigned q0 = ldbits(0), q1 = ldbits(1), q2 = ldbits(2), q3 = ldbits(3);

    for (int t = 0; t < T_STEPS; t += 4) {
        const int sw = t & 4;        // write slots sw..sw+3 (t..t+3)
        const int sr = 4 - sw;       // read slots (t-4..t-1)

        // produce first (MFMA latency hides under finisher VALU below)
        int4v aA = expand(q0);
        int4v aB = expand(q1);
        int4v aC = expand(q2);
        int4v aD = expand(q3);
        if (t + 4 < T_STEPS) {
            q0 = ldbits(t + 4);
            q1 = ldbits(t + 5);
            q2 = ldbits(t + 6);
            q3 = ldbits(t + 7);
        }
        wrpart(sw + 0, mci(aA));
        wrpart(sw + 1, mci(aB));
        wrpart(sw + 2, mci(aC));
        wrpart(sw + 3, mci(aD));

        // deferred LIF(t-4..t-1); slots sr.. are overwritten only next body
        if (fin && t > 0) {
            lif1(sr + 0);
            lif1(sr + 1);
            lif1(sr + 2);
            lif1(sr + 3);
        }
        __syncthreads();   // slots sw ready; reads of sr done
    }
    // epilogue: LIF(1020..1023) from slots 4..7 (last body wrote them)
    if (fin) {
        lif1(4);
        lif1(5);
        lif1(6);
        lif1(7);
        const size_t idx = (size_t)(b0 + lq * 4 + rown) * F_DIM + gw + mrow;
        out[idx]          = z0;
        out[BF + idx]     = v0;
        out[2 * BF + idx] = c0;
    }
}

// ---------------- fallback: R3 fp32-input kernel (verified) ----------------
__global__ __launch_bounds__(256, 1)
void lif_kernel_f32(const float* __restrict__ spikes,
                    const float* __restrict__ W,
                    float* __restrict__ out)
{
    __shared__ unsigned short sAf[16 * ROWP];
    __shared__ float xbuf[2 * 256];

    const int tid  = threadIdx.x;
    const int lane = tid & 63;
    const int w    = tid >> 6;
    const int gh   = w & 1;
    const int kh   = w >> 1;
    const int bt   = blockIdx.x & 15;
    const int gb   = blockIdx.x >> 4;
    const int b0   = bt * 16;
    const int gw   = gb * 32 + gh * 16;
    const int mrow = lane & 15;
    const int kq   = lane >> 4;

    short8 whi[8], wmd[8], wlo[8];
    {
        const float* wp = W + (size_t)(gw + mrow) * F_DIM + kh * 256 + kq * 8;
        #pragma unroll
        for (int ks = 0; ks < 8; ++ks) {
            short8 hi, md, lo;
            #pragma unroll
            for (int j = 0; j < 8; ++j) {
                float f = wp[ks * 32 + j];
                unsigned short h = f2bf_rne(f);
                float r1 = f - bf2f(h);
                unsigned short m = f2bf_rne(r1);
                float r2 = r1 - bf2f(m);
                hi[j] = (short)h;
                md[j] = (short)m;
                lo[j] = (short)f2bf_rne(r2);
            }
            whi[ks] = hi; wmd[ks] = md; wlo[ks] = lo;
        }
    }

    float v[4]  = {0.f, 0.f, 0.f, 0.f};
    float cu[4] = {0.f, 0.f, 0.f, 0.f};
    float zf[4] = {0.f, 0.f, 0.f, 0.f};

    floatx4 ld[8];
    auto issue_loads = [&](int t) {
        const floatx4* sp = (const floatx4*)(spikes + (size_t)t * BF + (size_t)b0 * F_DIM);
        #pragma unroll
        for (int j = 0; j < 8; ++j)
            ld[j] = sp[tid + 256 * j];
    };

    issue_loads(0);
    for (int t = 0; t < T_STEPS; ++t) {
        #pragma unroll
        for (int j = 0; j < 8; ++j) {
            const int q = tid + 256 * j;
            const int row = q >> 7, col4 = q & 127;
            unsigned u0 = __float_as_uint(ld[j][0]);
            unsigned u1 = __float_as_uint(ld[j][1]);
            unsigned u2 = __float_as_uint(ld[j][2]);
            unsigned u3 = __float_as_uint(ld[j][3]);
            uintx2 d;
            d[0] = (u0 >> 16) | (u1 & 0xFFFF0000u);
            d[1] = (u2 >> 16) | (u3 & 0xFFFF0000u);
            *(uintx2*)&sAf[row * ROWP + col4 * 4] = d;
        }
        __syncthreads();
        if (t + 1 < T_STEPS) issue_loads(t + 1);

        floatx4 ah = {0.f, 0.f, 0.f, 0.f};
        floatx4 am = {0.f, 0.f, 0.f, 0.f};
        floatx4 al = {0.f, 0.f, 0.f, 0.f};
        const unsigned short* arow = &sAf[mrow * ROWP + kh * 256 + kq * 8];
        #pragma unroll
        for (int ks = 0; ks < 8; ++ks) {
            short8 a = *(const short8*)(arow + ks * 32);
            ah = __builtin_amdgcn_mfma_f32_16x16x32_bf16(a, whi[ks], ah, 0, 0, 0);
            am = __builtin_amdgcn_mfma_f32_16x16x32_bf16(a, wmd[ks], am, 0, 0, 0);
            al = __builtin_amdgcn_mfma_f32_16x16x32_bf16(a, wlo[ks], al, 0, 0, 0);
        }

        if (kh == 1) {
            floatx4 xp = (ah + am) + al;
            *(floatx4*)&xbuf[gh * 256 + lane * 4] = xp;
        }
        __syncthreads();
        if (kh == 0) {
            floatx4 other = *(const floatx4*)&xbuf[gh * 256 + lane * 4];
            #pragma unroll
            for (int r = 0; r < 4; ++r) {
                float x    = ((ah[r] + am[r]) + al[r]) + other[r];
                float vdec = v[r] + 0.1f * ((0.0f - v[r]) + cu[r]);
                float idec = cu[r] - 0.2f * cu[r];
                bool  spk  = (vdec - 1.0f) > 0.0f;
                zf[r] = spk ? 1.0f : 0.0f;
                v[r]  = spk ? 0.0f : vdec;
                cu[r] = idec + x;
            }
        }
    }

    if (kh == 0) {
        #pragma unroll
        for (int r = 0; r < 4; ++r) {
            const size_t idx = (size_t)(b0 + kq * 4 + r) * F_DIM + gw + mrow;
            out[idx]          = zf[r];
            out[BF + idx]     = v[r];
            out[2 * BF + idx] = cu[r];
        }
    }
}

extern "C" void kernel_launch(void* const* d_in, const int* in_sizes, int n_in,
                              void* d_out, int out_size, void* d_ws, size_t ws_size,
                              hipStream_t stream)
{
    const float* spikes = (const float*)d_in[0];   // [T,B,F] fp32
    const float* W      = (const float*)d_in[1];   // [F,F]   fp32
    float* out          = (float*)d_out;           // [3,B,F] fp32

    const size_t need_bits = (size_t)T_STEPS * B_DIM * (F_DIM / 8);   // 16 MiB

    if (d_ws != nullptr && ws_size >= need_bits) {
        unsigned* bits = (unsigned*)d_ws;
        pack_kernel<<<dim3(2048), dim3(256), 0, stream>>>(spikes, bits);
        lif_kernel_bits<<<dim3(512), dim3(512), 0, stream>>>(bits, W, out);
    } else {
        lif_kernel_f32<<<dim3(256), dim3(256), 0, stream>>>(spikes, W, out);
    }
}